// Round 7
// baseline (614.781 us; speedup 1.0000x reference)
//
#include <hip/hip_runtime.h>
#include <hip/hip_bf16.h>
#include <stdint.h>

typedef __attribute__((ext_vector_type(8))) short short8;
typedef __attribute__((ext_vector_type(4))) float floatx4;

#define GLOAD_LDS16(gptr, lptr)                                                     \
  __builtin_amdgcn_global_load_lds(                                                 \
      (const __attribute__((address_space(1))) void*)(gptr),                        \
      (__attribute__((address_space(3))) void*)(lptr), 16, 0, 0)

#define FENCE() asm volatile("" ::: "memory")
#define BARRIER() do { FENCE(); __builtin_amdgcn_s_barrier(); FENCE(); } while (0)

__device__ inline void fwht16(float v[16]) {
#pragma unroll
    for (int s = 0; s < 4; ++s) {
        const int h = 1 << s;
#pragma unroll
        for (int k = 0; k < 16; k += 2 * h)
#pragma unroll
            for (int j = 0; j < h; ++j) {
                float a = v[k + j], b = v[k + j + h];
                v[k + j] = a + b;
                v[k + j + h] = a - b;
            }
    }
}

// ---------------------------------------------------------------------------
// Kernel 1: W_eff[o][i] = Wscale * D4_CB[Qidxs[o][i/4]][i%4] + sum_r A[o][r]*B[r][i]
// grid (16 i-tiles of 256, 64 o-tiles of 64), block 256.  (unchanged)
// ---------------------------------------------------------------------------
__global__ __launch_bounds__(256) void decode_weff(
    const int* __restrict__ Qidxs, const float* __restrict__ D4_CB,
    const float* __restrict__ Wscale_p, const float* __restrict__ A,
    const float* __restrict__ B, __hip_bfloat16* __restrict__ W_eff)
{
    __shared__ __align__(16) float As[64 * 64];   // A[oBase+oo][r]
    __shared__ __align__(16) float CB[256 * 4];
    const int t = threadIdx.x;
    const int oBase = blockIdx.y * 64;
    const int iBase = blockIdx.x * 256;

    const float4* A4 = (const float4*)(A + (long)oBase * 64);
    float4* As4 = (float4*)As;
#pragma unroll
    for (int u = 0; u < 4; ++u) As4[t + u * 256] = A4[t + u * 256];
    ((float4*)CB)[t] = ((const float4*)D4_CB)[t];
    __syncthreads();

    const float wscale = Wscale_p[0];
    const int i = iBase + t;
    float bcol[64];
#pragma unroll
    for (int r = 0; r < 64; ++r) bcol[r] = B[r * 4096 + i];

    const int g = i >> 2;
    const int sub = i & 3;

    for (int oo = 0; oo < 64; ++oo) {
        const int o = oBase + oo;
        const float4* arow = (const float4*)&As[oo * 64];
        float acc = 0.f;
#pragma unroll
        for (int r4 = 0; r4 < 16; ++r4) {
            float4 a4 = arow[r4];
            acc += a4.x * bcol[4 * r4 + 0] + a4.y * bcol[4 * r4 + 1] +
                   a4.z * bcol[4 * r4 + 2] + a4.w * bcol[4 * r4 + 3];
        }
        const int q = Qidxs[(long)o * 1024 + g];
        const float w = wscale * CB[q * 4 + sub] + acc;
        W_eff[(long)o * 4096 + i] = __float2bfloat16(w);
    }
}

// ---------------------------------------------------------------------------
// Kernel 2: per row: x/scaleWH*SU -> FWHT(4096) -> *1/64 -> bf16  (unchanged)
// ---------------------------------------------------------------------------
__global__ __launch_bounds__(256) void fwht_in_kernel(
    const float* __restrict__ x, const float* __restrict__ SU,
    const float* __restrict__ sWH, __hip_bfloat16* __restrict__ xh)
{
    __shared__ float row[4096 + 256];
    const int t = threadIdx.x;
    const long base = (long)blockIdx.x * 4096;
    float v[16];

#pragma unroll
    for (int u = 0; u < 16; ++u) {
        int e = u * 256 + t;
        v[u] = x[base + e] / sWH[e] * SU[e];
    }
    fwht16(v);
#pragma unroll
    for (int u = 0; u < 16; ++u) {
        int e = u * 256 + t;
        row[e + (e >> 4)] = v[u];
    }
    __syncthreads();

    const int lo = t & 15, hi = t >> 4;
#pragma unroll
    for (int u = 0; u < 16; ++u) v[u] = row[hi * 272 + u * 17 + lo];
    fwht16(v);
#pragma unroll
    for (int u = 0; u < 16; ++u) row[hi * 272 + u * 17 + lo] = v[u];
    __syncthreads();

#pragma unroll
    for (int u = 0; u < 16; ++u) v[u] = row[t * 17 + u];
    fwht16(v);

    short8 o0, o1;
#pragma unroll
    for (int u = 0; u < 8; ++u) {
        __hip_bfloat16 b = __float2bfloat16(v[u] * 0.015625f);
        o0[u] = *(short*)&b;
    }
#pragma unroll
    for (int u = 0; u < 8; ++u) {
        __hip_bfloat16 b = __float2bfloat16(v[8 + u] * 0.015625f);
        o1[u] = *(short*)&b;
    }
    *(short8*)(xh + base + t * 16) = o0;
    *(short8*)(xh + base + t * 16 + 8) = o1;
}

// ---------------------------------------------------------------------------
// Kernel 3: z[m][n] = sum_k xh[m][k] * W_eff[n][k]   (bf16 in, bf16 out)
// 256x256 tile, BK=64, 512 thr (2x4 waves, 128x64 out/wave), 8-phase schedule
// (T2 XOR swizzle + T3/T4 counted vmcnt + T5 setprio).
// R5 change: removed blunt lgkmcnt(0)+sched_barrier(0) pre-MFMA drains and the
// phase-0 lgkmcnt(8). ds_reads are compiler-visible short8 loads, so hipcc
// inserts fine-grained lgkmcnt(N) per MFMA operand (m97 evidence) and can
// interleave MFMA issue with tail-read latency + stage address VALU.
// Correctness: every ds_read issued in a phase is consumed by that phase's
// MFMA cluster, so all reads complete before the trailing barrier ->
// cross-wave stage-overwrite ordering (reads-done-before-stage-issue) holds.
// Stage stream per tile t: p0:Ah1(t+1) p1:Bh1(t+1) p2:Bh0(t+2) p3:Ah0(t+2).
// vmcnt(4) at tile end proves all of tile t+1 resident.
// ---------------------------------------------------------------------------
__global__ __launch_bounds__(512, 2) void gemm_bt(
    const __hip_bfloat16* __restrict__ xh,
    const __hip_bfloat16* __restrict__ wf,
    __hip_bfloat16* __restrict__ z)
{
    __shared__ __align__(16) __hip_bfloat16 sA[2][256 * 64];
    __shared__ __align__(16) __hip_bfloat16 sB[2][256 * 64];

    const int t = threadIdx.x;
    const int lane = t & 63;
    const int wv = t >> 6;            // 0..7
    const int wm = wv >> 2;           // 0..1  (M half of tile)
    const int wn = wv & 3;            // 0..3  (N quarter of tile)
    const long mBase = (long)blockIdx.y * 256;
    const long nBase = (long)blockIdx.x * 256;

    // --- staging: thread t covers rows (t>>3), LDS slot chunk (t&7);
    //     global chunk = slot ^ (row&7)  (pre-swizzled source, linear dest)
    const int grow = t >> 3;                       // 0..63 within an issue
    const int gcol = ((t & 7) ^ (grow & 7)) * 8;   // element offset in row
    const __hip_bfloat16* gA = xh + (mBase + grow) * 4096 + gcol;
    const __hip_bfloat16* gB = wf + (nBase + grow) * 4096 + gcol;
    const int lrow = wv * 8;          // wave's row base within an issue

    // --- fragment read offsets: frag row = base+fr, chunk q = kh*4+(lane>>4),
    //     LDS slot = q ^ (fr&7)
    const int fr = lane & 15;
    const int c2 = lane >> 4;                      // 0..3
    const int slot0 = ((c2 ^ (fr & 7)) * 8);       // kh=0 (elements); kh=1: ^32

    floatx4 acc[8][4] = {};
    short8 afr[4][2];   // current M-half fragments  (m x kh)
    short8 bfr[4][2];   // all 4 N fragments         (n x kh)

    // issue one 128-row half-tile (2 x global_load_lds dwordx4)
    auto stage = [&](int buf, int isA, int halfRow, int kt) {
        const __hip_bfloat16* g =
            (isA ? gA : gB) + (long)halfRow * 4096 + (long)kt * 64;
        __hip_bfloat16* l =
            (isA ? &sA[buf][0] : &sB[buf][0]) + (halfRow + lrow) * 64;
        GLOAD_LDS16(g, l);
        GLOAD_LDS16(g + 64L * 4096, l + 64 * 64);
    };
    auto ldA = [&](int buf, int mhalf) {   // 8 ds_read_b128
        const __hip_bfloat16* base =
            &sA[buf][0] + (wm * 128 + mhalf * 64 + fr) * 64;
#pragma unroll
        for (int m = 0; m < 4; ++m) {
            afr[m][0] = *(const short8*)(base + m * 16 * 64 + slot0);
            afr[m][1] = *(const short8*)(base + m * 16 * 64 + (slot0 ^ 32));
        }
    };
    auto ldB2 = [&](int buf, int npair) {  // 4 ds_read_b128
        const __hip_bfloat16* base =
            &sB[buf][0] + (wn * 64 + npair * 32 + fr) * 64;
#pragma unroll
        for (int n = 0; n < 2; ++n) {
            bfr[npair * 2 + n][0] = *(const short8*)(base + n * 16 * 64 + slot0);
            bfr[npair * 2 + n][1] = *(const short8*)(base + n * 16 * 64 + (slot0 ^ 32));
        }
    };
    auto mma16 = [&](int mh, int np) {     // 16 MFMA: one C-quadrant x K=64
#pragma unroll
        for (int m = 0; m < 4; ++m)
#pragma unroll
            for (int n = 0; n < 2; ++n)
#pragma unroll
                for (int kh = 0; kh < 2; ++kh)
                    acc[mh * 4 + m][np * 2 + n] =
                        __builtin_amdgcn_mfma_f32_16x16x32_bf16(
                            afr[m][kh], bfr[np * 2 + n][kh],
                            acc[mh * 4 + m][np * 2 + n], 0, 0, 0);
    };

    // --- prologue: tile0 fully + {Bh0,Ah0} of tile1; keep 2 halves in flight
    stage(0, 1, 0,   0);   // Ah0(0)
    stage(0, 1, 128, 0);   // Ah1(0)
    stage(0, 0, 0,   0);   // Bh0(0)
    stage(0, 0, 128, 0);   // Bh1(0)
    stage(1, 0, 0,   1);   // Bh0(1)
    stage(1, 1, 0,   1);   // Ah0(1)
    asm volatile("s_waitcnt vmcnt(4)" ::: "memory");
    BARRIER();

    for (int kt = 0; kt < 64; ++kt) {
        const int cur = kt & 1;

        // ---- phase 0: A m0-3 + B n0-1 (12 reads) | stage Ah1(t+1)
        ldA(cur, 0);
        ldB2(cur, 0);
        if (kt + 1 < 64) stage(cur ^ 1, 1, 128, kt + 1);
        BARRIER();
        __builtin_amdgcn_s_setprio(1);
        mma16(0, 0);
        __builtin_amdgcn_s_setprio(0);
        BARRIER();

        // ---- phase 1: B n2-3 (4 reads) | stage Bh1(t+1)
        ldB2(cur, 1);
        if (kt + 1 < 64) stage(cur ^ 1, 0, 128, kt + 1);
        BARRIER();
        __builtin_amdgcn_s_setprio(1);
        mma16(0, 1);
        __builtin_amdgcn_s_setprio(0);
        BARRIER();

        // ---- phase 2: A m4-7 (8 reads) | stage Bh0(t+2)  (B-buf dead)
        ldA(cur, 1);
        if (kt + 2 < 64) stage(cur, 0, 0, kt + 2);
        BARRIER();
        __builtin_amdgcn_s_setprio(1);
        mma16(1, 0);
        __builtin_amdgcn_s_setprio(0);
        BARRIER();

        // ---- phase 3: no reads | stage Ah0(t+2)  (A-buf dead)
        if (kt + 2 < 64) stage(cur, 1, 0, kt + 2);
        BARRIER();
        __builtin_amdgcn_s_setprio(1);
        mma16(1, 1);
        __builtin_amdgcn_s_setprio(0);
        if (kt < 62) asm volatile("s_waitcnt vmcnt(4)" ::: "memory");
        else         asm volatile("s_waitcnt vmcnt(0)" ::: "memory");
        BARRIER();
    }

    // ---- epilogue: C/D layout col=lane&15, row=(lane>>4)*4+reg
    const int q4 = c2 * 4;
#pragma unroll
    for (int m = 0; m < 8; ++m)
#pragma unroll
        for (int n = 0; n < 4; ++n)
#pragma unroll
            for (int r = 0; r < 4; ++r) {
                const long row = mBase + wm * 128 + m * 16 + q4 + r;
                const long col = nBase + wn * 64 + n * 16 + fr;
                z[row * 4096 + col] = __float2bfloat16(acc[m][n][r]);
            }
}

// ---------------------------------------------------------------------------
// Kernel 4: per row: bf16 z -> FWHT(4096) -> *SV/64 -> fp32 out  (unchanged)
// ---------------------------------------------------------------------------
__global__ __launch_bounds__(256) void fwht_out_kernel(
    const __hip_bfloat16* __restrict__ z, const float* __restrict__ SV,
    float* __restrict__ out)
{
    __shared__ float row[4096 + 256];
    const int t = threadIdx.x;
    const long base = (long)blockIdx.x * 4096;
    float v[16];

#pragma unroll
    for (int u = 0; u < 16; ++u) {
        int e = u * 256 + t;
        v[u] = __bfloat162float(z[base + e]);
    }
    fwht16(v);
#pragma unroll
    for (int u = 0; u < 16; ++u) {
        int e = u * 256 + t;
        row[e + (e >> 4)] = v[u];
    }
    __syncthreads();

    const int lo = t & 15, hi = t >> 4;
#pragma unroll
    for (int u = 0; u < 16; ++u) v[u] = row[hi * 272 + u * 17 + lo];
    fwht16(v);
#pragma unroll
    for (int u = 0; u < 16; ++u) row[hi * 272 + u * 17 + lo] = v[u];
    __syncthreads();

#pragma unroll
    for (int u = 0; u < 16; ++u) v[u] = row[t * 17 + u];
    fwht16(v);

    const float4* svv = (const float4*)(SV + t * 16);
    float4* ov = (float4*)(out + base + t * 16);
#pragma unroll
    for (int c = 0; c < 4; ++c) {
        float4 s = svv[c];
        float4 f;
        f.x = v[4 * c + 0] * s.x * 0.015625f;
        f.y = v[4 * c + 1] * s.y * 0.015625f;
        f.z = v[4 * c + 2] * s.z * 0.015625f;
        f.w = v[4 * c + 3] * s.w * 0.015625f;
        ov[c] = f;
    }
}

// ---------------------------------------------------------------------------
extern "C" void kernel_launch(void* const* d_in, const int* in_sizes, int n_in,
                              void* d_out, int out_size, void* d_ws, size_t ws_size,
                              hipStream_t stream)
{
    const float* input  = (const float*)d_in[0];
    const int*   Qidxs  = (const int*)d_in[1];
    const float* D4_CB  = (const float*)d_in[2];
    const float* SU     = (const float*)d_in[3];
    const float* SV     = (const float*)d_in[4];
    const float* Wscale = (const float*)d_in[5];
    const float* A      = (const float*)d_in[6];
    const float* B      = (const float*)d_in[7];
    const float* sWH    = (const float*)d_in[8];
    float* out = (float*)d_out;

    char* ws = (char*)d_ws;
    __hip_bfloat16* weff = (__hip_bfloat16*)ws;                               // 32 MiB
    __hip_bfloat16* xh   = (__hip_bfloat16*)(ws + (32L << 20));               // 64 MiB
    __hip_bfloat16* zbuf = (__hip_bfloat16*)(ws + (32L << 20) + (64L << 20)); // 64 MiB

    decode_weff<<<dim3(16, 64), 256, 0, stream>>>(Qidxs, D4_CB, Wscale, A, B, weff);
    fwht_in_kernel<<<8192, 256, 0, stream>>>(input, SU, sWH, xh);
    gemm_bt<<<dim3(16, 32), 512, 0, stream>>>(xh, weff, zbuf);
    fwht_out_kernel<<<8192, 256, 0, stream>>>(zbuf, SV, out);
}

// Round 9
// 605.275 us; speedup vs baseline: 1.0157x; 1.0157x over previous
//
#include <hip/hip_runtime.h>
#include <hip/hip_bf16.h>
#include <stdint.h>

typedef __attribute__((ext_vector_type(8))) short short8;
typedef __attribute__((ext_vector_type(4))) float floatx4;

#define GLOAD_LDS16(gptr, lptr)                                                     \
  __builtin_amdgcn_global_load_lds(                                                 \
      (const __attribute__((address_space(1))) void*)(gptr),                        \
      (__attribute__((address_space(3))) void*)(lptr), 16, 0, 0)

#define FENCE() asm volatile("" ::: "memory")
#define BARRIER() do { FENCE(); __builtin_amdgcn_s_barrier(); FENCE(); } while (0)
// Phase end: pin MFMA + its operand waits above (sched_barrier), prove this
// wave's ds_reads retired (lgkmcnt(0) — free, already drained by MFMA operand
// waits), then the single trailing barrier that provides cross-wave
// stage-vs-read safety.
#define PHASE_END() do { __builtin_amdgcn_sched_barrier(0);                        \
                         asm volatile("s_waitcnt lgkmcnt(0)" ::: "memory");        \
                         __builtin_amdgcn_s_barrier();                             \
                         __builtin_amdgcn_sched_barrier(0); } while (0)

__device__ inline void fwht16(float v[16]) {
#pragma unroll
    for (int s = 0; s < 4; ++s) {
        const int h = 1 << s;
#pragma unroll
        for (int k = 0; k < 16; k += 2 * h)
#pragma unroll
            for (int j = 0; j < h; ++j) {
                float a = v[k + j], b = v[k + j + h];
                v[k + j] = a + b;
                v[k + j + h] = a - b;
            }
    }
}

// ---------------------------------------------------------------------------
// Kernel 1: W_eff[o][i] = Wscale * D4_CB[Qidxs[o][i/4]][i%4] + sum_r A[o][r]*B[r][i]
// grid (16 i-tiles of 256, 64 o-tiles of 64), block 256.  (unchanged)
// ---------------------------------------------------------------------------
__global__ __launch_bounds__(256) void decode_weff(
    const int* __restrict__ Qidxs, const float* __restrict__ D4_CB,
    const float* __restrict__ Wscale_p, const float* __restrict__ A,
    const float* __restrict__ B, __hip_bfloat16* __restrict__ W_eff)
{
    __shared__ __align__(16) float As[64 * 64];   // A[oBase+oo][r]
    __shared__ __align__(16) float CB[256 * 4];
    const int t = threadIdx.x;
    const int oBase = blockIdx.y * 64;
    const int iBase = blockIdx.x * 256;

    const float4* A4 = (const float4*)(A + (long)oBase * 64);
    float4* As4 = (float4*)As;
#pragma unroll
    for (int u = 0; u < 4; ++u) As4[t + u * 256] = A4[t + u * 256];
    ((float4*)CB)[t] = ((const float4*)D4_CB)[t];
    __syncthreads();

    const float wscale = Wscale_p[0];
    const int i = iBase + t;
    float bcol[64];
#pragma unroll
    for (int r = 0; r < 64; ++r) bcol[r] = B[r * 4096 + i];

    const int g = i >> 2;
    const int sub = i & 3;

    for (int oo = 0; oo < 64; ++oo) {
        const int o = oBase + oo;
        const float4* arow = (const float4*)&As[oo * 64];
        float acc = 0.f;
#pragma unroll
        for (int r4 = 0; r4 < 16; ++r4) {
            float4 a4 = arow[r4];
            acc += a4.x * bcol[4 * r4 + 0] + a4.y * bcol[4 * r4 + 1] +
                   a4.z * bcol[4 * r4 + 2] + a4.w * bcol[4 * r4 + 3];
        }
        const int q = Qidxs[(long)o * 1024 + g];
        const float w = wscale * CB[q * 4 + sub] + acc;
        W_eff[(long)o * 4096 + i] = __float2bfloat16(w);
    }
}

// ---------------------------------------------------------------------------
// Kernel 2: per row: x/scaleWH*SU -> FWHT(4096) -> *1/64 -> bf16  (unchanged)
// ---------------------------------------------------------------------------
__global__ __launch_bounds__(256) void fwht_in_kernel(
    const float* __restrict__ x, const float* __restrict__ SU,
    const float* __restrict__ sWH, __hip_bfloat16* __restrict__ xh)
{
    __shared__ float row[4096 + 256];
    const int t = threadIdx.x;
    const long base = (long)blockIdx.x * 4096;
    float v[16];

#pragma unroll
    for (int u = 0; u < 16; ++u) {
        int e = u * 256 + t;
        v[u] = x[base + e] / sWH[e] * SU[e];
    }
    fwht16(v);
#pragma unroll
    for (int u = 0; u < 16; ++u) {
        int e = u * 256 + t;
        row[e + (e >> 4)] = v[u];
    }
    __syncthreads();

    const int lo = t & 15, hi = t >> 4;
#pragma unroll
    for (int u = 0; u < 16; ++u) v[u] = row[hi * 272 + u * 17 + lo];
    fwht16(v);
#pragma unroll
    for (int u = 0; u < 16; ++u) row[hi * 272 + u * 17 + lo] = v[u];
    __syncthreads();

#pragma unroll
    for (int u = 0; u < 16; ++u) v[u] = row[t * 17 + u];
    fwht16(v);

    short8 o0, o1;
#pragma unroll
    for (int u = 0; u < 8; ++u) {
        __hip_bfloat16 b = __float2bfloat16(v[u] * 0.015625f);
        o0[u] = *(short*)&b;
    }
#pragma unroll
    for (int u = 0; u < 8; ++u) {
        __hip_bfloat16 b = __float2bfloat16(v[8 + u] * 0.015625f);
        o1[u] = *(short*)&b;
    }
    *(short8*)(xh + base + t * 16) = o0;
    *(short8*)(xh + base + t * 16 + 8) = o1;
}

// ---------------------------------------------------------------------------
// Kernel 3: z[m][n] = sum_k xh[m][k] * W_eff[n][k]   (bf16 in, bf16 out)
// 256x256 tile, BK=64, 512 thr (2x4 waves, 128x64 out/wave).
// R7 change: SINGLE barrier per phase (trailing only). The leading barrier
// was not needed for correctness: stage-vs-read safety comes from the
// trailing barrier (a wave cannot pass it until its MFMA operand waits
// retire its ds_reads; the conflicting stage is issued only after it).
// Removing it lets waves slip within a phase, overlapping one wave's
// ds_reads with another's MFMA (previously serialized block-wide).
// sched_barrier(0)+lgkmcnt(0) before each s_barrier pins MFMA above the
// barrier (rule-18 class hazard: compiler sinking register-only MFMA past
// inline-asm barriers).
// Stage stream per tile t: p0:Ah1(t+1) p1:Bh1(t+1) p2:Bh0(t+2) p3:Ah0(t+2).
// Region safety: Bh0(t+2) after p1-barrier (all B-reads done), Ah0(t+2)
// after p2-barrier (all A-reads done), t+1 halves vs kt t-1's barriers.
// vmcnt(4) at tile end proves all of tile t+1 resident (4 newest loads are
// the t+2 halves).
// ---------------------------------------------------------------------------
__global__ __launch_bounds__(512, 2) void gemm_bt(
    const __hip_bfloat16* __restrict__ xh,
    const __hip_bfloat16* __restrict__ wf,
    __hip_bfloat16* __restrict__ z)
{
    __shared__ __align__(16) __hip_bfloat16 sA[2][256 * 64];
    __shared__ __align__(16) __hip_bfloat16 sB[2][256 * 64];

    const int t = threadIdx.x;
    const int lane = t & 63;
    const int wv = t >> 6;            // 0..7
    const int wm = wv >> 2;           // 0..1  (M half of tile)
    const int wn = wv & 3;            // 0..3  (N quarter of tile)
    const long mBase = (long)blockIdx.y * 256;
    const long nBase = (long)blockIdx.x * 256;

    // --- staging: thread t covers rows (t>>3), LDS slot chunk (t&7);
    //     global chunk = slot ^ (row&7)  (pre-swizzled source, linear dest)
    const int grow = t >> 3;                       // 0..63 within an issue
    const int gcol = ((t & 7) ^ (grow & 7)) * 8;   // element offset in row
    const __hip_bfloat16* gA = xh + (mBase + grow) * 4096 + gcol;
    const __hip_bfloat16* gB = wf + (nBase + grow) * 4096 + gcol;
    const int lrow = wv * 8;          // wave's row base within an issue

    // --- fragment read offsets: frag row = base+fr, chunk q = kh*4+(lane>>4),
    //     LDS slot = q ^ (fr&7)
    const int fr = lane & 15;
    const int c2 = lane >> 4;                      // 0..3
    const int slot0 = ((c2 ^ (fr & 7)) * 8);       // kh=0 (elements); kh=1: ^32

    floatx4 acc[8][4] = {};
    short8 afr[4][2];   // current M-half fragments  (m x kh)
    short8 bfr[4][2];   // all 4 N fragments         (n x kh)

    // issue one 128-row half-tile (2 x global_load_lds dwordx4)
    auto stage = [&](int buf, int isA, int halfRow, int kt) {
        const __hip_bfloat16* g =
            (isA ? gA : gB) + (long)halfRow * 4096 + (long)kt * 64;
        __hip_bfloat16* l =
            (isA ? &sA[buf][0] : &sB[buf][0]) + (halfRow + lrow) * 64;
        GLOAD_LDS16(g, l);
        GLOAD_LDS16(g + 64L * 4096, l + 64 * 64);
    };
    auto ldA = [&](int buf, int mhalf) {   // 8 ds_read_b128
        const __hip_bfloat16* base =
            &sA[buf][0] + (wm * 128 + mhalf * 64 + fr) * 64;
#pragma unroll
        for (int m = 0; m < 4; ++m) {
            afr[m][0] = *(const short8*)(base + m * 16 * 64 + slot0);
            afr[m][1] = *(const short8*)(base + m * 16 * 64 + (slot0 ^ 32));
        }
    };
    auto ldB2 = [&](int buf, int npair) {  // 4 ds_read_b128
        const __hip_bfloat16* base =
            &sB[buf][0] + (wn * 64 + npair * 32 + fr) * 64;
#pragma unroll
        for (int n = 0; n < 2; ++n) {
            bfr[npair * 2 + n][0] = *(const short8*)(base + n * 16 * 64 + slot0);
            bfr[npair * 2 + n][1] = *(const short8*)(base + n * 16 * 64 + (slot0 ^ 32));
        }
    };
    auto mma16 = [&](int mh, int np) {     // 16 MFMA: one C-quadrant x K=64
#pragma unroll
        for (int m = 0; m < 4; ++m)
#pragma unroll
            for (int n = 0; n < 2; ++n)
#pragma unroll
                for (int kh = 0; kh < 2; ++kh)
                    acc[mh * 4 + m][np * 2 + n] =
                        __builtin_amdgcn_mfma_f32_16x16x32_bf16(
                            afr[m][kh], bfr[np * 2 + n][kh],
                            acc[mh * 4 + m][np * 2 + n], 0, 0, 0);
    };

    // --- prologue: tile0 fully + {Bh0,Ah0} of tile1; keep 2 halves in flight
    stage(0, 1, 0,   0);   // Ah0(0)
    stage(0, 1, 128, 0);   // Ah1(0)
    stage(0, 0, 0,   0);   // Bh0(0)
    stage(0, 0, 128, 0);   // Bh1(0)
    stage(1, 0, 0,   1);   // Bh0(1)
    stage(1, 1, 0,   1);   // Ah0(1)
    asm volatile("s_waitcnt vmcnt(4)" ::: "memory");
    BARRIER();

    for (int kt = 0; kt < 64; ++kt) {
        const int cur = kt & 1;

        // ---- phase 0: A m0-3 + B n0-1 (12 reads) | stage Ah1(t+1) | MFMA q00
        ldA(cur, 0);
        ldB2(cur, 0);
        if (kt + 1 < 64) stage(cur ^ 1, 1, 128, kt + 1);
        __builtin_amdgcn_s_setprio(1);
        mma16(0, 0);
        __builtin_amdgcn_s_setprio(0);
        PHASE_END();

        // ---- phase 1: B n2-3 (4 reads) | stage Bh1(t+1) | MFMA q01
        ldB2(cur, 1);
        if (kt + 1 < 64) stage(cur ^ 1, 0, 128, kt + 1);
        __builtin_amdgcn_s_setprio(1);
        mma16(0, 1);
        __builtin_amdgcn_s_setprio(0);
        PHASE_END();

        // ---- phase 2: A m4-7 (8 reads) | stage Bh0(t+2) (B-buf dead) | MFMA q10
        ldA(cur, 1);
        if (kt + 2 < 64) stage(cur, 0, 0, kt + 2);
        __builtin_amdgcn_s_setprio(1);
        mma16(1, 0);
        __builtin_amdgcn_s_setprio(0);
        PHASE_END();

        // ---- phase 3: no reads | stage Ah0(t+2) (A-buf dead) | MFMA q11
        if (kt + 2 < 64) stage(cur, 1, 0, kt + 2);
        __builtin_amdgcn_s_setprio(1);
        mma16(1, 1);
        __builtin_amdgcn_s_setprio(0);
        __builtin_amdgcn_sched_barrier(0);
        if (kt < 62) asm volatile("s_waitcnt vmcnt(4) lgkmcnt(0)" ::: "memory");
        else         asm volatile("s_waitcnt vmcnt(0) lgkmcnt(0)" ::: "memory");
        __builtin_amdgcn_s_barrier();
        __builtin_amdgcn_sched_barrier(0);
    }

    // ---- epilogue: C/D layout col=lane&15, row=(lane>>4)*4+reg
    const int q4 = c2 * 4;
#pragma unroll
    for (int m = 0; m < 8; ++m)
#pragma unroll
        for (int n = 0; n < 4; ++n)
#pragma unroll
            for (int r = 0; r < 4; ++r) {
                const long row = mBase + wm * 128 + m * 16 + q4 + r;
                const long col = nBase + wn * 64 + n * 16 + fr;
                z[row * 4096 + col] = __float2bfloat16(acc[m][n][r]);
            }
}

// ---------------------------------------------------------------------------
// Kernel 4: per row: bf16 z -> FWHT(4096) -> *SV/64 -> fp32 out  (unchanged)
// ---------------------------------------------------------------------------
__global__ __launch_bounds__(256) void fwht_out_kernel(
    const __hip_bfloat16* __restrict__ z, const float* __restrict__ SV,
    float* __restrict__ out)
{
    __shared__ float row[4096 + 256];
    const int t = threadIdx.x;
    const long base = (long)blockIdx.x * 4096;
    float v[16];

#pragma unroll
    for (int u = 0; u < 16; ++u) {
        int e = u * 256 + t;
        v[u] = __bfloat162float(z[base + e]);
    }
    fwht16(v);
#pragma unroll
    for (int u = 0; u < 16; ++u) {
        int e = u * 256 + t;
        row[e + (e >> 4)] = v[u];
    }
    __syncthreads();

    const int lo = t & 15, hi = t >> 4;
#pragma unroll
    for (int u = 0; u < 16; ++u) v[u] = row[hi * 272 + u * 17 + lo];
    fwht16(v);
#pragma unroll
    for (int u = 0; u < 16; ++u) row[hi * 272 + u * 17 + lo] = v[u];
    __syncthreads();

#pragma unroll
    for (int u = 0; u < 16; ++u) v[u] = row[t * 17 + u];
    fwht16(v);

    const float4* svv = (const float4*)(SV + t * 16);
    float4* ov = (float4*)(out + base + t * 16);
#pragma unroll
    for (int c = 0; c < 4; ++c) {
        float4 s = svv[c];
        float4 f;
        f.x = v[4 * c + 0] * s.x * 0.015625f;
        f.y = v[4 * c + 1] * s.y * 0.015625f;
        f.z = v[4 * c + 2] * s.z * 0.015625f;
        f.w = v[4 * c + 3] * s.w * 0.015625f;
        ov[c] = f;
    }
}

// ---------------------------------------------------------------------------
extern "C" void kernel_launch(void* const* d_in, const int* in_sizes, int n_in,
                              void* d_out, int out_size, void* d_ws, size_t ws_size,
                              hipStream_t stream)
{
    const float* input  = (const float*)d_in[0];
    const int*   Qidxs  = (const int*)d_in[1];
    const float* D4_CB  = (const float*)d_in[2];
    const float* SU     = (const float*)d_in[3];
    const float* SV     = (const float*)d_in[4];
    const float* Wscale = (const float*)d_in[5];
    const float* A      = (const float*)d_in[6];
    const float* B      = (const float*)d_in[7];
    const float* sWH    = (const float*)d_in[8];
    float* out = (float*)d_out;

    char* ws = (char*)d_ws;
    __hip_bfloat16* weff = (__hip_bfloat16*)ws;                               // 32 MiB
    __hip_bfloat16* xh   = (__hip_bfloat16*)(ws + (32L << 20));               // 64 MiB
    __hip_bfloat16* zbuf = (__hip_bfloat16*)(ws + (32L << 20) + (64L << 20)); // 64 MiB

    decode_weff<<<dim3(16, 64), 256, 0, stream>>>(Qidxs, D4_CB, Wscale, A, B, weff);
    fwht_in_kernel<<<8192, 256, 0, stream>>>(input, SU, sWH, xh);
    gemm_bt<<<dim3(16, 32), 512, 0, stream>>>(xh, weff, zbuf);
    fwht_out_kernel<<<8192, 256, 0, stream>>>(zbuf, SV, out);
}

// Round 11
// 552.121 us; speedup vs baseline: 1.1135x; 1.0963x over previous
//
#include <hip/hip_runtime.h>
#include <hip/hip_bf16.h>
#include <stdint.h>

typedef __attribute__((ext_vector_type(8))) short short8;
typedef __attribute__((ext_vector_type(4))) float floatx4;

#define GLOAD_LDS16(gptr, lptr)                                                     \
  __builtin_amdgcn_global_load_lds(                                                 \
      (const __attribute__((address_space(1))) void*)(gptr),                        \
      (__attribute__((address_space(3))) void*)(lptr), 16, 0, 0)

#define FENCE() asm volatile("" ::: "memory")
#define BARRIER() do { FENCE(); __builtin_amdgcn_s_barrier(); FENCE(); } while (0)
#define PHASE_END() do { __builtin_amdgcn_sched_barrier(0);                        \
                         asm volatile("s_waitcnt lgkmcnt(0)" ::: "memory");        \
                         __builtin_amdgcn_s_barrier();                             \
                         __builtin_amdgcn_sched_barrier(0); } while (0)

__device__ inline void fwht16(float v[16]) {
#pragma unroll
    for (int s = 0; s < 4; ++s) {
        const int h = 1 << s;
#pragma unroll
        for (int k = 0; k < 16; k += 2 * h)
#pragma unroll
            for (int j = 0; j < h; ++j) {
                float a = v[k + j], b = v[k + j + h];
                v[k + j] = a + b;
                v[k + j + h] = a - b;
            }
    }
}

// ---------------------------------------------------------------------------
// Kernel 1 (R9 rewrite): W_eff = Wscale*CB[Qidxs] + (A@B) via bf16 MFMA.
// Rank-64 term ~0.03 on W~0.9 already bf16-rounded -> bf16-input error
// negligible. Replaces LDS-issue-bound oo-loop (1024 ds_read_b128/thread).
// Tile 256(o) x 256(i), K=64 single tile; 512 thr, 8 waves (2Mx4N),
// per-wave 128x64. LDS pad stride 72 bf16 breaks stride-64 bank alignment.
// ---------------------------------------------------------------------------
__global__ __launch_bounds__(512) void decode_mfma(
    const int* __restrict__ Qidxs, const float* __restrict__ D4_CB,
    const float* __restrict__ Wscale_p, const float* __restrict__ A,
    const float* __restrict__ B, __hip_bfloat16* __restrict__ W_eff)
{
    __shared__ __align__(16) __hip_bfloat16 la[256 * 72];
    __shared__ __align__(16) __hip_bfloat16 lbt[256 * 72];
    __shared__ __align__(16) float CBs[1024];

    const int t = threadIdx.x;
    const int lane = t & 63;
    const int wv = t >> 6;
    const int wm = wv >> 2;           // 0..1  (o-half)
    const int wn = wv & 3;            // 0..3  (i-quarter)
    const long oBase = (long)blockIdx.y * 256;
    const long iBase = (long)blockIdx.x * 256;

    // stage A: A[oBase+row][r] fp32 -> la[row*72+r] bf16 (coalesced float4)
#pragma unroll
    for (int u = 0; u < 8; ++u) {
        int el4 = u * 512 + t;          // float4 index, 4096 total
        int row = el4 >> 4;
        int r   = (el4 & 15) * 4;
        float4 v = *(const float4*)(A + (oBase + row) * 64 + r);
        __hip_bfloat16* d = &la[row * 72 + r];
        d[0] = __float2bfloat16(v.x); d[1] = __float2bfloat16(v.y);
        d[2] = __float2bfloat16(v.z); d[3] = __float2bfloat16(v.w);
    }
    // stage B^T: B[r][iBase+j] -> lbt[j*72+r] bf16 (coalesced per r-row)
#pragma unroll
    for (int u = 0; u < 32; ++u) {
        int el = u * 512 + t;           // 0..16383
        int r = el >> 8;
        int j = el & 255;
        lbt[j * 72 + r] = __float2bfloat16(B[(long)r * 4096 + iBase + j]);
    }
    if (t < 256) ((float4*)CBs)[t] = ((const float4*)D4_CB)[t];
    __syncthreads();

    const float wscale = Wscale_p[0];
    const int fr = lane & 15;
    const int c2 = lane >> 4;
    floatx4 acc[8][4] = {};
    short8 af[4][2], bfx[4][2];

#pragma unroll
    for (int n = 0; n < 4; ++n)
#pragma unroll
        for (int kh = 0; kh < 2; ++kh)
            bfx[n][kh] = *(const short8*)&lbt[(wn * 64 + n * 16 + fr) * 72 + kh * 32 + c2 * 8];

#pragma unroll
    for (int mh = 0; mh < 2; ++mh) {
#pragma unroll
        for (int m = 0; m < 4; ++m)
#pragma unroll
            for (int kh = 0; kh < 2; ++kh)
                af[m][kh] = *(const short8*)&la[(wm * 128 + mh * 64 + m * 16 + fr) * 72 + kh * 32 + c2 * 8];
#pragma unroll
        for (int m = 0; m < 4; ++m)
#pragma unroll
            for (int n = 0; n < 4; ++n)
#pragma unroll
                for (int kh = 0; kh < 2; ++kh)
                    acc[mh * 4 + m][n] = __builtin_amdgcn_mfma_f32_16x16x32_bf16(
                        af[m][kh], bfx[n][kh], acc[mh * 4 + m][n], 0, 0, 0);
    }

    // epilogue: C/D layout col=lane&15, row=(lane>>4)*4+reg (verified mapping)
    const int q4 = c2 * 4;
#pragma unroll
    for (int m = 0; m < 8; ++m)
#pragma unroll
        for (int n = 0; n < 4; ++n)
#pragma unroll
            for (int rr = 0; rr < 4; ++rr) {
                const long o = oBase + wm * 128 + m * 16 + q4 + rr;
                const long i = iBase + wn * 64 + n * 16 + fr;
                const int q = Qidxs[o * 1024 + (i >> 2)];
                const float w = wscale * CBs[q * 4 + (i & 3)] + acc[m][n][rr];
                W_eff[o * 4096 + i] = __float2bfloat16(w);
            }
}

// ---------------------------------------------------------------------------
// Kernel 2: per row: x/scaleWH*SU -> FWHT(4096) -> *1/64 -> bf16  (unchanged)
// ---------------------------------------------------------------------------
__global__ __launch_bounds__(256) void fwht_in_kernel(
    const float* __restrict__ x, const float* __restrict__ SU,
    const float* __restrict__ sWH, __hip_bfloat16* __restrict__ xh)
{
    __shared__ float row[4096 + 256];
    const int t = threadIdx.x;
    const long base = (long)blockIdx.x * 4096;
    float v[16];

#pragma unroll
    for (int u = 0; u < 16; ++u) {
        int e = u * 256 + t;
        v[u] = x[base + e] / sWH[e] * SU[e];
    }
    fwht16(v);
#pragma unroll
    for (int u = 0; u < 16; ++u) {
        int e = u * 256 + t;
        row[e + (e >> 4)] = v[u];
    }
    __syncthreads();

    const int lo = t & 15, hi = t >> 4;
#pragma unroll
    for (int u = 0; u < 16; ++u) v[u] = row[hi * 272 + u * 17 + lo];
    fwht16(v);
#pragma unroll
    for (int u = 0; u < 16; ++u) row[hi * 272 + u * 17 + lo] = v[u];
    __syncthreads();

#pragma unroll
    for (int u = 0; u < 16; ++u) v[u] = row[t * 17 + u];
    fwht16(v);

    short8 o0, o1;
#pragma unroll
    for (int u = 0; u < 8; ++u) {
        __hip_bfloat16 b = __float2bfloat16(v[u] * 0.015625f);
        o0[u] = *(short*)&b;
    }
#pragma unroll
    for (int u = 0; u < 8; ++u) {
        __hip_bfloat16 b = __float2bfloat16(v[8 + u] * 0.015625f);
        o1[u] = *(short*)&b;
    }
    *(short8*)(xh + base + t * 16) = o0;
    *(short8*)(xh + base + t * 16 + 8) = o1;
}

// ---------------------------------------------------------------------------
// Kernel 3: z[m][n] = sum_k xh[m][k] * W_eff[n][k]   (bf16 in, bf16 out)
// 256x256 tile, BK=64, 512 thr. R7 single-trailing-barrier schedule —
// UNCHANGED from the measured 265.6 µs / 45.1% MfmaUtil state.
// ---------------------------------------------------------------------------
__global__ __launch_bounds__(512, 2) void gemm_bt(
    const __hip_bfloat16* __restrict__ xh,
    const __hip_bfloat16* __restrict__ wf,
    __hip_bfloat16* __restrict__ z)
{
    __shared__ __align__(16) __hip_bfloat16 sA[2][256 * 64];
    __shared__ __align__(16) __hip_bfloat16 sB[2][256 * 64];

    const int t = threadIdx.x;
    const int lane = t & 63;
    const int wv = t >> 6;
    const int wm = wv >> 2;
    const int wn = wv & 3;
    const long mBase = (long)blockIdx.y * 256;
    const long nBase = (long)blockIdx.x * 256;

    const int grow = t >> 3;
    const int gcol = ((t & 7) ^ (grow & 7)) * 8;
    const __hip_bfloat16* gA = xh + (mBase + grow) * 4096 + gcol;
    const __hip_bfloat16* gB = wf + (nBase + grow) * 4096 + gcol;
    const int lrow = wv * 8;

    const int fr = lane & 15;
    const int c2 = lane >> 4;
    const int slot0 = ((c2 ^ (fr & 7)) * 8);

    floatx4 acc[8][4] = {};
    short8 afr[4][2];
    short8 bfr[4][2];

    auto stage = [&](int buf, int isA, int halfRow, int kt) {
        const __hip_bfloat16* g =
            (isA ? gA : gB) + (long)halfRow * 4096 + (long)kt * 64;
        __hip_bfloat16* l =
            (isA ? &sA[buf][0] : &sB[buf][0]) + (halfRow + lrow) * 64;
        GLOAD_LDS16(g, l);
        GLOAD_LDS16(g + 64L * 4096, l + 64 * 64);
    };
    auto ldA = [&](int buf, int mhalf) {
        const __hip_bfloat16* base =
            &sA[buf][0] + (wm * 128 + mhalf * 64 + fr) * 64;
#pragma unroll
        for (int m = 0; m < 4; ++m) {
            afr[m][0] = *(const short8*)(base + m * 16 * 64 + slot0);
            afr[m][1] = *(const short8*)(base + m * 16 * 64 + (slot0 ^ 32));
        }
    };
    auto ldB2 = [&](int buf, int npair) {
        const __hip_bfloat16* base =
            &sB[buf][0] + (wn * 64 + npair * 32 + fr) * 64;
#pragma unroll
        for (int n = 0; n < 2; ++n) {
            bfr[npair * 2 + n][0] = *(const short8*)(base + n * 16 * 64 + slot0);
            bfr[npair * 2 + n][1] = *(const short8*)(base + n * 16 * 64 + (slot0 ^ 32));
        }
    };
    auto mma16 = [&](int mh, int np) {
#pragma unroll
        for (int m = 0; m < 4; ++m)
#pragma unroll
            for (int n = 0; n < 2; ++n)
#pragma unroll
                for (int kh = 0; kh < 2; ++kh)
                    acc[mh * 4 + m][np * 2 + n] =
                        __builtin_amdgcn_mfma_f32_16x16x32_bf16(
                            afr[m][kh], bfr[np * 2 + n][kh],
                            acc[mh * 4 + m][np * 2 + n], 0, 0, 0);
    };

    stage(0, 1, 0,   0);
    stage(0, 1, 128, 0);
    stage(0, 0, 0,   0);
    stage(0, 0, 128, 0);
    stage(1, 0, 0,   1);
    stage(1, 1, 0,   1);
    asm volatile("s_waitcnt vmcnt(4)" ::: "memory");
    BARRIER();

    for (int kt = 0; kt < 64; ++kt) {
        const int cur = kt & 1;

        ldA(cur, 0);
        ldB2(cur, 0);
        if (kt + 1 < 64) stage(cur ^ 1, 1, 128, kt + 1);
        __builtin_amdgcn_s_setprio(1);
        mma16(0, 0);
        __builtin_amdgcn_s_setprio(0);
        PHASE_END();

        ldB2(cur, 1);
        if (kt + 1 < 64) stage(cur ^ 1, 0, 128, kt + 1);
        __builtin_amdgcn_s_setprio(1);
        mma16(0, 1);
        __builtin_amdgcn_s_setprio(0);
        PHASE_END();

        ldA(cur, 1);
        if (kt + 2 < 64) stage(cur, 0, 0, kt + 2);
        __builtin_amdgcn_s_setprio(1);
        mma16(1, 0);
        __builtin_amdgcn_s_setprio(0);
        PHASE_END();

        if (kt + 2 < 64) stage(cur, 1, 0, kt + 2);
        __builtin_amdgcn_s_setprio(1);
        mma16(1, 1);
        __builtin_amdgcn_s_setprio(0);
        __builtin_amdgcn_sched_barrier(0);
        if (kt < 62) asm volatile("s_waitcnt vmcnt(4) lgkmcnt(0)" ::: "memory");
        else         asm volatile("s_waitcnt vmcnt(0) lgkmcnt(0)" ::: "memory");
        __builtin_amdgcn_s_barrier();
        __builtin_amdgcn_sched_barrier(0);
    }

    const int q4 = c2 * 4;
#pragma unroll
    for (int m = 0; m < 8; ++m)
#pragma unroll
        for (int n = 0; n < 4; ++n)
#pragma unroll
            for (int r = 0; r < 4; ++r) {
                const long row = mBase + wm * 128 + m * 16 + q4 + r;
                const long col = nBase + wn * 64 + n * 16 + fr;
                z[row * 4096 + col] = __float2bfloat16(acc[m][n][r]);
            }
}

// ---------------------------------------------------------------------------
// Kernel 4: per row: bf16 z -> FWHT(4096) -> *SV/64 -> fp32 out  (unchanged)
// ---------------------------------------------------------------------------
__global__ __launch_bounds__(256) void fwht_out_kernel(
    const __hip_bfloat16* __restrict__ z, const float* __restrict__ SV,
    float* __restrict__ out)
{
    __shared__ float row[4096 + 256];
    const int t = threadIdx.x;
    const long base = (long)blockIdx.x * 4096;
    float v[16];

#pragma unroll
    for (int u = 0; u < 16; ++u) {
        int e = u * 256 + t;
        v[u] = __bfloat162float(z[base + e]);
    }
    fwht16(v);
#pragma unroll
    for (int u = 0; u < 16; ++u) {
        int e = u * 256 + t;
        row[e + (e >> 4)] = v[u];
    }
    __syncthreads();

    const int lo = t & 15, hi = t >> 4;
#pragma unroll
    for (int u = 0; u < 16; ++u) v[u] = row[hi * 272 + u * 17 + lo];
    fwht16(v);
#pragma unroll
    for (int u = 0; u < 16; ++u) row[hi * 272 + u * 17 + lo] = v[u];
    __syncthreads();

#pragma unroll
    for (int u = 0; u < 16; ++u) v[u] = row[t * 17 + u];
    fwht16(v);

    const float4* svv = (const float4*)(SV + t * 16);
    float4* ov = (float4*)(out + base + t * 16);
#pragma unroll
    for (int c = 0; c < 4; ++c) {
        float4 s = svv[c];
        float4 f;
        f.x = v[4 * c + 0] * s.x * 0.015625f;
        f.y = v[4 * c + 1] * s.y * 0.015625f;
        f.z = v[4 * c + 2] * s.z * 0.015625f;
        f.w = v[4 * c + 3] * s.w * 0.015625f;
        ov[c] = f;
    }
}

// ---------------------------------------------------------------------------
extern "C" void kernel_launch(void* const* d_in, const int* in_sizes, int n_in,
                              void* d_out, int out_size, void* d_ws, size_t ws_size,
                              hipStream_t stream)
{
    const float* input  = (const float*)d_in[0];
    const int*   Qidxs  = (const int*)d_in[1];
    const float* D4_CB  = (const float*)d_in[2];
    const float* SU     = (const float*)d_in[3];
    const float* SV     = (const float*)d_in[4];
    const float* Wscale = (const float*)d_in[5];
    const float* A      = (const float*)d_in[6];
    const float* B      = (const float*)d_in[7];
    const float* sWH    = (const float*)d_in[8];
    float* out = (float*)d_out;

    char* ws = (char*)d_ws;
    __hip_bfloat16* weff = (__hip_bfloat16*)ws;                               // 32 MiB
    __hip_bfloat16* xh   = (__hip_bfloat16*)(ws + (32L << 20));               // 64 MiB
    __hip_bfloat16* zbuf = (__hip_bfloat16*)(ws + (32L << 20) + (64L << 20)); // 64 MiB

    decode_mfma<<<dim3(16, 16), 512, 0, stream>>>(Qidxs, D4_CB, Wscale, A, B, weff);
    fwht_in_kernel<<<8192, 256, 0, stream>>>(input, SU, sWH, xh);
    gemm_bt<<<dim3(16, 32), 512, 0, stream>>>(xh, weff, zbuf);
    fwht_out_kernel<<<8192, 256, 0, stream>>>(zbuf, SV, out);
}